// Round 7
// baseline (324.771 us; speedup 1.0000x reference)
//
#include <hip/hip_runtime.h>
#include <hip/hip_bf16.h>

#define L_SEQ 40
#define B_SZ  16
#define V_SZ  10000
#define V_PAD 10240
#define NPAIR 780
#define NROWP 784                 // 780 pairs + 1 init row + 3 pad "pairs"
#define M_ROWS (NROWP * B_SZ)     // 12544 rows = 49 strips of 256

typedef __attribute__((ext_vector_type(4))) float f32x4;
typedef __attribute__((ext_vector_type(2))) long lng2;

// ---------------------------------------------------------------------------
// float -> OCP e4m3fn. Prefer HW cvt; hand-rolled RNE fallback.
// ---------------------------------------------------------------------------
#if __has_builtin(__builtin_amdgcn_cvt_pk_fp8_f32)
__device__ __forceinline__ unsigned int pack4_fp8(float x0, float x1, float x2, float x3) {
    int lo = __builtin_amdgcn_cvt_pk_fp8_f32(x0, x1, 0, false);
    int full = __builtin_amdgcn_cvt_pk_fp8_f32(x2, x3, lo, true);
    return (unsigned int)full;
}
#else
__device__ __forceinline__ unsigned char f2e4m3(float f) {
    unsigned u = __float_as_uint(f);
    unsigned s = (u >> 24) & 0x80u;
    if ((u & 0x7FFFFFFFu) == 0) return (unsigned char)s;
    int E = (int)((u >> 23) & 0xFF) - 127 + 7;
    unsigned m = u & 0x7FFFFFu;
    if (E >= 16) return (unsigned char)(s | 0x7E);
    if (E >= 1) {
        unsigned keep = m >> 20, rest = m & 0xFFFFFu;
        keep += (rest > 0x80000u) || (rest == 0x80000u && (keep & 1));
        if (keep == 8) { keep = 0; E++; if (E >= 16) return (unsigned char)(s | 0x7E); }
        return (unsigned char)(s | (E << 3) | keep);
    }
    int shift = 1 - E;
    if (shift > 10) return (unsigned char)s;
    unsigned full = 0x800000u | m;
    unsigned sh = 20 + shift;
    unsigned keep = full >> sh, rem = full & ((1u << sh) - 1), half = 1u << (sh - 1);
    keep += (rem > half) || (rem == half && (keep & 1));
    if (keep >= 8) return (unsigned char)(s | (1 << 3));
    return (unsigned char)(s | keep);
}
__device__ __forceinline__ unsigned int pack4_fp8(float x0, float x1, float x2, float x3) {
    return (unsigned int)f2e4m3(x0) | ((unsigned int)f2e4m3(x1) << 8)
         | ((unsigned int)f2e4m3(x2) << 16) | ((unsigned int)f2e4m3(x3) << 24);
}
#endif

// fast tanh via HW exp: tanh(x) = (e^{2x}-1)/(e^{2x}+1). err ~1e-7, ~6 VALU ops.
__device__ __forceinline__ float ftanh(float x) {
    x = fminf(20.f, fmaxf(-20.f, x));
    float t = __expf(2.f * x);
    return (t - 1.f) * __frcp_rn(t + 1.f);
}

// PK layout: byte k of a 256-B row stored at pos = p*64 + l4*16 + h*8 + j
// where k = (2p+h)*32 + l4*8 + j. A lane's 16 B at (p, l4) covers the two
// k-steps 2p (low 8B) and 2p+1 (high 8B) of its MFMA fragment.

// ---------------------------------------------------------------------------
// K1: fused prep. [0,2560): transpose Ww2 -> WwT fp32 [10240,256] + WbT fp8 PK;
//     [2560,2880): UV = h @ {Wt1,Ww1} halves; rest: zero rowsum.
// ---------------------------------------------------------------------------
__global__ __launch_bounds__(256) void prep_kernel(
        const float* __restrict__ Ww2, float* __restrict__ WwT,
        unsigned char* __restrict__ WbT,
        const float* __restrict__ h, const float* __restrict__ Wt1,
        const float* __restrict__ Ww1, float* __restrict__ UV,
        float* __restrict__ rowsum) {
    const int bx = blockIdx.x;
    const int t = threadIdx.x;
    __shared__ float tile[32][33];
    __shared__ float hs[8 * 512];
    if (bx < 2560) {
        int v0 = (bx % 320) * 32;
        int K8 = bx / 320;           // k-tile index, k0 = K8*32
        int k0 = K8 * 32;
        int tx = t & 31, ty = t >> 5;   // 32 x 8
#pragma unroll
        for (int r = 0; r < 4; r++) {
            int k = k0 + ty + r * 8;
            int v = v0 + tx;
            tile[ty + r * 8][tx] = (v < V_SZ) ? Ww2[k * V_SZ + v] : 0.0f;   // tile[k][v]
        }
        __syncthreads();
        // fp32 transposed write
#pragma unroll
        for (int r = 0; r < 4; r++) {
            int vrow = ty + r * 8;
            WwT[(v0 + vrow) * 256 + (k0 + tx)] = tile[tx][vrow];
        }
        // fp8 PK write: thread -> (col v2, 4 consecutive k)
        int v2 = t >> 3;                 // 0..31
        int kq = 4 * (t & 7);            // local k base 0..28
        unsigned int pk = pack4_fp8(tile[kq][v2], tile[kq + 1][v2],
                                    tile[kq + 2][v2], tile[kq + 3][v2]);
        // PK uint index for global k = K8*32 + kq:
        int idx = (K8 >> 1) * 16 + ((t & 7) >> 1) * 4 + (K8 & 1) * 2 + (t & 1);
        ((unsigned int*)WbT)[(v0 + v2) * 64 + idx] = pk;
    } else if (bx < 2880) {
        int ub = bx - 2560;
        int which = ub / 80;         // 0:Ut 1:Vt 2:Uw 3:Vw
        int m0 = (ub % 80) * 8;
        const float4* src = (const float4*)(h + (size_t)m0 * 512);
        float4* dst4 = (float4*)hs;
#pragma unroll
        for (int v = 0; v < 4; v++) dst4[v * 256 + t] = src[v * 256 + t];
        __syncthreads();
        const float* W = ((which < 2) ? Wt1 : Ww1) + ((which & 1) ? 512 * 256 : 0);
        float acc[8] = {};
        for (int f = 0; f < 512; f += 4) {
            float w0 = W[(f + 0) * 256 + t];
            float w1 = W[(f + 1) * 256 + t];
            float w2 = W[(f + 2) * 256 + t];
            float w3 = W[(f + 3) * 256 + t];
#pragma unroll
            for (int r = 0; r < 8; r++) {
                acc[r] += hs[r * 512 + f] * w0 + hs[r * 512 + f + 1] * w1
                        + hs[r * 512 + f + 2] * w2 + hs[r * 512 + f + 3] * w3;
            }
        }
        float* dst = UV + ((size_t)which * 640 + m0) * 256;
#pragma unroll
        for (int r = 0; r < 8; r++) dst[r * 256 + t] = acc[r];
    } else {
        int idx = (bx - 2880) * 256 + t;
        if (idx < M_ROWS) rowsum[idx] = 0.0f;
    }
}

// ---------------------------------------------------------------------------
// K2: per (pair,b) row: X = fp8(tanh(Uw[i]+Vw[j]+bw1)) in PK order;
//     tlog/glog fp32 exact. One wave per row; p==780 is the init cell.
// ---------------------------------------------------------------------------
__global__ void build_rows(const float* __restrict__ UV,
                           const int* __restrict__ sentence,
                           const float* __restrict__ bt1,
                           const float* __restrict__ bw1,
                           const float* __restrict__ Wt2,
                           const float* __restrict__ bt2,
                           const float* __restrict__ WwT,
                           const float* __restrict__ bw2,
                           unsigned char* __restrict__ X,
                           float* __restrict__ tlog,
                           float* __restrict__ glog) {
    int w = blockIdx.x * 4 + (threadIdx.x >> 6);
    int lane = threadIdx.x & 63;
    int p = w >> 4, b = w & 15;
    int i = 0, j = 0;
    if (p < NPAIR) {
        int rem = p, len = L_SEQ - 1;
        while (rem >= len) { rem -= len; len--; i++; }
        j = i + 1 + rem;
    }
    int j1 = (j + 1 < L_SEQ) ? j + 1 : L_SEQ - 1;
    int tgt = sentence[j1 * B_SZ + b];
    const float4 ut = ((const float4*)(UV + 0 * 640 * 256 + (i * B_SZ + b) * 256))[lane];
    const float4 vt = ((const float4*)(UV + 1 * 640 * 256 + (j * B_SZ + b) * 256))[lane];
    const float4 uw = ((const float4*)(UV + 2 * 640 * 256 + (i * B_SZ + b) * 256))[lane];
    const float4 vw = ((const float4*)(UV + 3 * 640 * 256 + (j * B_SZ + b) * 256))[lane];
    const float4 bt = ((const float4*)bt1)[lane];
    const float4 bw = ((const float4*)bw1)[lane];
    const float4 w2 = ((const float4*)Wt2)[lane];
    const float4 wc = ((const float4*)(WwT + (size_t)tgt * 256))[lane];
    float xt0 = ftanh(ut.x + vt.x + bt.x), xt1 = ftanh(ut.y + vt.y + bt.y);
    float xt2 = ftanh(ut.z + vt.z + bt.z), xt3 = ftanh(ut.w + vt.w + bt.w);
    float xw0 = ftanh(uw.x + vw.x + bw.x), xw1 = ftanh(uw.y + vw.y + bw.y);
    float xw2 = ftanh(uw.z + vw.z + bw.z), xw3 = ftanh(uw.w + vw.w + bw.w);
    // PK uint index for k0 = lane*4:
    int pki = (lane >> 4) * 16 + ((lane >> 1) & 3) * 4 + ((lane >> 3) & 1) * 2 + (lane & 1);
    ((unsigned int*)X)[w * 64 + pki] = pack4_fp8(xw0, xw1, xw2, xw3);
    float td = xt0 * w2.x + xt1 * w2.y + xt2 * w2.z + xt3 * w2.w;
    float gd = xw0 * wc.x + xw1 * wc.y + xw2 * wc.z + xw3 * wc.w;
#pragma unroll
    for (int off = 32; off >= 1; off >>= 1) {
        td += __shfl_xor(td, off);
        gd += __shfl_xor(gd, off);
    }
    if (lane == 0) {
        tlog[w] = td + bt2[0];
        glog[w] = gd + bw2[tgt];
    }
}

// ---------------------------------------------------------------------------
// K3: fp8 GEMM + fused sum-exp, A-in-registers, high-occupancy.
// Grid (40 col-groups, 49 row-strips) = 1960 blocks, 4 waves/block.
// EACH WAVE OWNS A DISTINCT 64-ROW SLICE (row0 = by*256 + wid*64 — the R6
// bug was two waves sharing a slice => rowsum doubled). All 4 waves share
// the 64-col B tile (16 KB, double-buffered, 32 KB LDS -> 3 blocks/CU).
// A panel (64 rows x K=256 fp8) in 64 VGPRs, loaded once (PK layout).
// 4 iterations of 64 cols; one barrier/iter; exp into per-lane PS; one
// butterfly + 16 atomics per wave at end. Swizzle: 0 conflicts (verified R5).
// ---------------------------------------------------------------------------
__global__ __launch_bounds__(256, 3) void big_gemm(
        const unsigned char* __restrict__ X,
        const unsigned char* __restrict__ WbT,
        const float* __restrict__ bw2,
        float* __restrict__ rowsum) {
    __shared__ unsigned char Bs[2][64 * 256];    // 2 x 16 KB
    const int t = threadIdx.x;
    const int wid = t >> 6, lane = t & 63;
    const int l15 = lane & 15, l4 = lane >> 4;
    const int g = blockIdx.x;                    // col group: 4 tiles of 64
    const int row0 = blockIdx.y * 256 + wid * 64;  // wave's own 64 rows

    auto dmaB = [&](int buf, int tileIdx) {
        const unsigned char* Bg = WbT + (size_t)tileIdx * 64 * 256;
#pragma unroll
        for (int q = 0; q < 4; q++) {
            int base = q * 4096 + wid * 1024;    // wave-uniform dest
            int F = base + lane * 16;            // this lane's dest byte
            int cc = F >> 8;                     // dest col within tile
            int s = (F >> 4) & 15;               // dest granule slot
            int srcg = s ^ (cc & 15);            // swizzled source granule
            __builtin_amdgcn_global_load_lds(
                (const __attribute__((address_space(1))) unsigned int*)(Bg + cc * 256 + (srcg << 4)),
                (__attribute__((address_space(3))) unsigned int*)(&Bs[buf][0] + base),
                16, 0, 0);
        }
    };

    dmaB(0, g * 4);

    // ---- A panel: 64 rows x K=256 in 64 VGPRs (PK layout: direct 16B loads)
    lng2 apan[4][4];
    {
        const unsigned char* Ag = X + (size_t)row0 * 256;
#pragma unroll
        for (int mi = 0; mi < 4; mi++)
#pragma unroll
            for (int p = 0; p < 4; p++)
                apan[mi][p] = *(const lng2*)(Ag + (mi * 16 + l15) * 256 + p * 64 + l4 * 16);
    }
    __syncthreads();   // drains DMA for iter 0 too

    float PS[4][4] = {};

#pragma unroll 1
    for (int it = 0; it < 4; it++) {
        if (it < 3) dmaB((it + 1) & 1, g * 4 + it + 1);
        const unsigned char* Bb = &Bs[it & 1][0];
        f32x4 acc[4][4] = {};
#pragma unroll
        for (int p = 0; p < 4; p++) {
            lng2 b[4];
#pragma unroll
            for (int ni = 0; ni < 4; ni++) {
                int cc = ni * 16 + l15;
                b[ni] = *(const lng2*)(Bb + cc * 256 + (((p * 4 + l4) ^ (cc & 15)) << 4));
            }
#pragma unroll
            for (int mi = 0; mi < 4; mi++)
#pragma unroll
                for (int ni = 0; ni < 4; ni++) {
                    acc[mi][ni] = __builtin_amdgcn_mfma_f32_16x16x32_fp8_fp8(
                        apan[mi][p].x, b[ni].x, acc[mi][ni], 0, 0, 0);
                    acc[mi][ni] = __builtin_amdgcn_mfma_f32_16x16x32_fp8_fp8(
                        apan[mi][p].y, b[ni].y, acc[mi][ni], 0, 0, 0);
                }
        }
        // ---- epilogue: exp(logit + bias) into per-lane partials ----
#pragma unroll
        for (int ni = 0; ni < 4; ni++) {
            int col = (g * 4 + it) * 64 + ni * 16 + l15;
            float bias = (col < V_SZ) ? bw2[col] : -__builtin_inff();
#pragma unroll
            for (int mi = 0; mi < 4; mi++)
#pragma unroll
                for (int r = 0; r < 4; r++)
                    PS[mi][r] += __expf(acc[mi][ni][r] + bias);
        }
        __syncthreads();
    }
    // ---- one butterfly + atomics per wave ----
#pragma unroll
    for (int mi = 0; mi < 4; mi++)
#pragma unroll
        for (int r = 0; r < 4; r++) {
            float v = PS[mi][r];
            v += __shfl_xor(v, 1); v += __shfl_xor(v, 2);
            v += __shfl_xor(v, 4); v += __shfl_xor(v, 8);
            if (l15 == 0)
                atomicAdd(&rowsum[row0 + mi * 16 + l4 * 4 + r], v);
        }
}

// ---------------------------------------------------------------------------
// K4: build tables in LDS + CKY DP. 16 blocks (one per batch), ONE WAVE
// each (wave-synchronous: barriers are single-wave = ~free). One lane per
// cell i (n_i <= 38 < 64), serial split loop with online logsumexp.
// ---------------------------------------------------------------------------
__global__ __launch_bounds__(64) void dp_kernel(const float* __restrict__ tlog,
                          const float* __restrict__ glog,
                          const float* __restrict__ rowsum,
                          float* __restrict__ out) {
    __shared__ float Tl[1600], SHWl[1600], REl[1600];
    const int t = threadIdx.x;
    const int b = blockIdx.x;
    const float NEGINF = -__builtin_inff();
    for (int idx = t; idx < 1600; idx += 64) {
        Tl[idx] = NEGINF; SHWl[idx] = NEGINF; REl[idx] = NEGINF;
    }
    __syncthreads();
    for (int p = t; p < NPAIR; p += 64) {
        int i = 0, rem = p, len = L_SEQ - 1;
        while (rem >= len) { rem -= len; len--; i++; }
        int j = i + 1 + rem;
        int row = p * 16 + b;
        float tl = tlog[row];
        float re_v = (tl >= 0.f) ? -log1pf(__expf(-tl)) : (tl - log1pf(__expf(tl)));
        float sh_v = (tl <= 0.f) ? -log1pf(__expf(tl)) : (-tl - log1pf(__expf(-tl)));
        float wlp = glog[row] - __logf(rowsum[row]);
        SHWl[i * 40 + j] = sh_v + wlp;
        REl[i * 40 + j] = re_v;
    }
    if (t == 0) {
        int row = NPAIR * 16 + b;           // init cell
        Tl[0 * 40 + 1] = glog[row] - __logf(rowsum[row]);
    }
    if (t >= 1 && t <= 38) Tl[t * 40 + t + 1] = 0.f;
    __syncthreads();
    for (int gap = 2; gap <= L_SEQ - 1; gap++) {
        int n_i = L_SEQ - gap;
        int i = t, j = t + gap;
        float m = NEGINF, s = 0.f;
        if (i < n_i) {
            for (int k = i + 1; k < j; k++) {
                float v = Tl[i * 40 + k] + Tl[k * 40 + j]
                        + SHWl[i * 40 + k] + REl[k * 40 + j];
                if (v > m) { s = s * __expf(m - v) + 1.f; m = v; }
                else s += __expf(v - m);
            }
        }
        __syncthreads();
        if (i < n_i) Tl[i * 40 + j] = m + __logf(s);
        __syncthreads();
    }
    if (t == 0) out[b] = Tl[39];
}

// ---------------------------------------------------------------------------
extern "C" void kernel_launch(void* const* d_in, const int* in_sizes, int n_in,
                              void* d_out, int out_size, void* d_ws, size_t ws_size,
                              hipStream_t stream) {
    const float* h        = (const float*)d_in[0];
    const int*   sentence = (const int*)d_in[1];
    const float* Wt1      = (const float*)d_in[2];
    const float* bt1      = (const float*)d_in[3];
    const float* Wt2      = (const float*)d_in[4];
    const float* bt2      = (const float*)d_in[5];
    const float* Ww1      = (const float*)d_in[6];
    const float* bw1      = (const float*)d_in[7];
    const float* Ww2      = (const float*)d_in[8];
    const float* bw2      = (const float*)d_in[9];
    float* out = (float*)d_out;

    char* ws = (char*)d_ws;
    size_t off = 0;
    float* UV = (float*)(ws + off);                    off += 4ull * 640 * 256 * 4;
    unsigned char* X = (unsigned char*)(ws + off);     off += (size_t)M_ROWS * 256;
    unsigned char* WbT = (unsigned char*)(ws + off);   off += (size_t)V_PAD * 256;
    float* WwT = (float*)(ws + off);                   off += (size_t)V_PAD * 256 * 4;
    float* rowsum = (float*)(ws + off);                off += (size_t)M_ROWS * 4;
    float* tlog = (float*)(ws + off);                  off += (size_t)M_ROWS * 4;
    float* glog = (float*)(ws + off);                  off += (size_t)M_ROWS * 4;

    const int zero_blocks = (M_ROWS + 255) / 256;      // 49
    prep_kernel<<<2880 + zero_blocks, 256, 0, stream>>>(
        Ww2, WwT, WbT, h, Wt1, Ww1, UV, rowsum);
    build_rows<<<M_ROWS / 4, 256, 0, stream>>>(UV, sentence, bt1, bw1, Wt2, bt2,
                                               WwT, bw2, X, tlog, glog);
    big_gemm<<<dim3(40, 49), 256, 0, stream>>>(X, WbT, bw2, rowsum);
    dp_kernel<<<16, 64, 0, stream>>>(tlog, glog, rowsum, out);
}

// Round 8
// 281.407 us; speedup vs baseline: 1.1541x; 1.1541x over previous
//
#include <hip/hip_runtime.h>
#include <hip/hip_bf16.h>

#define L_SEQ 40
#define B_SZ  16
#define V_SZ  10000
#define V_PAD 10240
#define NPAIR 780
#define NROWP 784                 // 780 pairs + 1 init row + 3 pad "pairs"
#define M_ROWS (NROWP * B_SZ)     // 12544 rows = 49 strips of 256

typedef __attribute__((ext_vector_type(4))) float f32x4;
typedef __attribute__((ext_vector_type(2))) long lng2;

// ---------------------------------------------------------------------------
// float -> OCP e4m3fn. Prefer HW cvt; hand-rolled RNE fallback.
// ---------------------------------------------------------------------------
#if __has_builtin(__builtin_amdgcn_cvt_pk_fp8_f32)
__device__ __forceinline__ unsigned int pack4_fp8(float x0, float x1, float x2, float x3) {
    int lo = __builtin_amdgcn_cvt_pk_fp8_f32(x0, x1, 0, false);
    int full = __builtin_amdgcn_cvt_pk_fp8_f32(x2, x3, lo, true);
    return (unsigned int)full;
}
#else
__device__ __forceinline__ unsigned char f2e4m3(float f) {
    unsigned u = __float_as_uint(f);
    unsigned s = (u >> 24) & 0x80u;
    if ((u & 0x7FFFFFFFu) == 0) return (unsigned char)s;
    int E = (int)((u >> 23) & 0xFF) - 127 + 7;
    unsigned m = u & 0x7FFFFFu;
    if (E >= 16) return (unsigned char)(s | 0x7E);
    if (E >= 1) {
        unsigned keep = m >> 20, rest = m & 0xFFFFFu;
        keep += (rest > 0x80000u) || (rest == 0x80000u && (keep & 1));
        if (keep == 8) { keep = 0; E++; if (E >= 16) return (unsigned char)(s | 0x7E); }
        return (unsigned char)(s | (E << 3) | keep);
    }
    int shift = 1 - E;
    if (shift > 10) return (unsigned char)s;
    unsigned full = 0x800000u | m;
    unsigned sh = 20 + shift;
    unsigned keep = full >> sh, rem = full & ((1u << sh) - 1), half = 1u << (sh - 1);
    keep += (rem > half) || (rem == half && (keep & 1));
    if (keep >= 8) return (unsigned char)(s | (1 << 3));
    return (unsigned char)(s | keep);
}
__device__ __forceinline__ unsigned int pack4_fp8(float x0, float x1, float x2, float x3) {
    return (unsigned int)f2e4m3(x0) | ((unsigned int)f2e4m3(x1) << 8)
         | ((unsigned int)f2e4m3(x2) << 16) | ((unsigned int)f2e4m3(x3) << 24);
}
#endif

// fast tanh via HW exp: tanh(x) = (e^{2x}-1)/(e^{2x}+1). err ~1e-7, ~6 VALU ops.
__device__ __forceinline__ float ftanh(float x) {
    x = fminf(20.f, fmaxf(-20.f, x));
    float t = __expf(2.f * x);
    return (t - 1.f) * __frcp_rn(t + 1.f);
}

// PK layout: byte k of a 256-B row stored at pos = p*64 + l4*16 + h*8 + j
// where k = (2p+h)*32 + l4*8 + j. A lane's 16 B at (p, l4) covers the two
// k-steps 2p (low 8B) and 2p+1 (high 8B) of its MFMA fragment.

// ---------------------------------------------------------------------------
// K1: fused prep. [0,2560): transpose Ww2 -> WwT fp32 [10240,256] + WbT fp8 PK;
//     [2560,2880): UV = h @ {Wt1,Ww1} halves; rest: zero rowsum.
// ---------------------------------------------------------------------------
__global__ __launch_bounds__(256) void prep_kernel(
        const float* __restrict__ Ww2, float* __restrict__ WwT,
        unsigned char* __restrict__ WbT,
        const float* __restrict__ h, const float* __restrict__ Wt1,
        const float* __restrict__ Ww1, float* __restrict__ UV,
        float* __restrict__ rowsum) {
    const int bx = blockIdx.x;
    const int t = threadIdx.x;
    __shared__ float tile[32][33];
    __shared__ float hs[8 * 512];
    if (bx < 2560) {
        int v0 = (bx % 320) * 32;
        int K8 = bx / 320;           // k-tile index, k0 = K8*32
        int k0 = K8 * 32;
        int tx = t & 31, ty = t >> 5;   // 32 x 8
#pragma unroll
        for (int r = 0; r < 4; r++) {
            int k = k0 + ty + r * 8;
            int v = v0 + tx;
            tile[ty + r * 8][tx] = (v < V_SZ) ? Ww2[k * V_SZ + v] : 0.0f;   // tile[k][v]
        }
        __syncthreads();
        // fp32 transposed write
#pragma unroll
        for (int r = 0; r < 4; r++) {
            int vrow = ty + r * 8;
            WwT[(v0 + vrow) * 256 + (k0 + tx)] = tile[tx][vrow];
        }
        // fp8 PK write: thread -> (col v2, 4 consecutive k)
        int v2 = t >> 3;                 // 0..31
        int kq = 4 * (t & 7);            // local k base 0..28
        unsigned int pk = pack4_fp8(tile[kq][v2], tile[kq + 1][v2],
                                    tile[kq + 2][v2], tile[kq + 3][v2]);
        // PK uint index for global k = K8*32 + kq:
        int idx = (K8 >> 1) * 16 + ((t & 7) >> 1) * 4 + (K8 & 1) * 2 + (t & 1);
        ((unsigned int*)WbT)[(v0 + v2) * 64 + idx] = pk;
    } else if (bx < 2880) {
        int ub = bx - 2560;
        int which = ub / 80;         // 0:Ut 1:Vt 2:Uw 3:Vw
        int m0 = (ub % 80) * 8;
        const float4* src = (const float4*)(h + (size_t)m0 * 512);
        float4* dst4 = (float4*)hs;
#pragma unroll
        for (int v = 0; v < 4; v++) dst4[v * 256 + t] = src[v * 256 + t];
        __syncthreads();
        const float* W = ((which < 2) ? Wt1 : Ww1) + ((which & 1) ? 512 * 256 : 0);
        float acc[8] = {};
        for (int f = 0; f < 512; f += 4) {
            float w0 = W[(f + 0) * 256 + t];
            float w1 = W[(f + 1) * 256 + t];
            float w2 = W[(f + 2) * 256 + t];
            float w3 = W[(f + 3) * 256 + t];
#pragma unroll
            for (int r = 0; r < 8; r++) {
                acc[r] += hs[r * 512 + f] * w0 + hs[r * 512 + f + 1] * w1
                        + hs[r * 512 + f + 2] * w2 + hs[r * 512 + f + 3] * w3;
            }
        }
        float* dst = UV + ((size_t)which * 640 + m0) * 256;
#pragma unroll
        for (int r = 0; r < 8; r++) dst[r * 256 + t] = acc[r];
    } else {
        int idx = (bx - 2880) * 256 + t;
        if (idx < M_ROWS) rowsum[idx] = 0.0f;
    }
}

// ---------------------------------------------------------------------------
// K2: per (pair,b) row: X = fp8(tanh(Uw[i]+Vw[j]+bw1)) in PK order;
//     tlog/glog fp32 exact. One wave per row; p==780 is the init cell.
// ---------------------------------------------------------------------------
__global__ void build_rows(const float* __restrict__ UV,
                           const int* __restrict__ sentence,
                           const float* __restrict__ bt1,
                           const float* __restrict__ bw1,
                           const float* __restrict__ Wt2,
                           const float* __restrict__ bt2,
                           const float* __restrict__ WwT,
                           const float* __restrict__ bw2,
                           unsigned char* __restrict__ X,
                           float* __restrict__ tlog,
                           float* __restrict__ glog) {
    int w = blockIdx.x * 4 + (threadIdx.x >> 6);
    int lane = threadIdx.x & 63;
    int p = w >> 4, b = w & 15;
    int i = 0, j = 0;
    if (p < NPAIR) {
        int rem = p, len = L_SEQ - 1;
        while (rem >= len) { rem -= len; len--; i++; }
        j = i + 1 + rem;
    }
    int j1 = (j + 1 < L_SEQ) ? j + 1 : L_SEQ - 1;
    int tgt = sentence[j1 * B_SZ + b];
    const float4 ut = ((const float4*)(UV + 0 * 640 * 256 + (i * B_SZ + b) * 256))[lane];
    const float4 vt = ((const float4*)(UV + 1 * 640 * 256 + (j * B_SZ + b) * 256))[lane];
    const float4 uw = ((const float4*)(UV + 2 * 640 * 256 + (i * B_SZ + b) * 256))[lane];
    const float4 vw = ((const float4*)(UV + 3 * 640 * 256 + (j * B_SZ + b) * 256))[lane];
    const float4 bt = ((const float4*)bt1)[lane];
    const float4 bw = ((const float4*)bw1)[lane];
    const float4 w2 = ((const float4*)Wt2)[lane];
    const float4 wc = ((const float4*)(WwT + (size_t)tgt * 256))[lane];
    float xt0 = ftanh(ut.x + vt.x + bt.x), xt1 = ftanh(ut.y + vt.y + bt.y);
    float xt2 = ftanh(ut.z + vt.z + bt.z), xt3 = ftanh(ut.w + vt.w + bt.w);
    float xw0 = ftanh(uw.x + vw.x + bw.x), xw1 = ftanh(uw.y + vw.y + bw.y);
    float xw2 = ftanh(uw.z + vw.z + bw.z), xw3 = ftanh(uw.w + vw.w + bw.w);
    // PK uint index for k0 = lane*4:
    int pki = (lane >> 4) * 16 + ((lane >> 1) & 3) * 4 + ((lane >> 3) & 1) * 2 + (lane & 1);
    ((unsigned int*)X)[w * 64 + pki] = pack4_fp8(xw0, xw1, xw2, xw3);
    float td = xt0 * w2.x + xt1 * w2.y + xt2 * w2.z + xt3 * w2.w;
    float gd = xw0 * wc.x + xw1 * wc.y + xw2 * wc.z + xw3 * wc.w;
#pragma unroll
    for (int off = 32; off >= 1; off >>= 1) {
        td += __shfl_xor(td, off);
        gd += __shfl_xor(gd, off);
    }
    if (lane == 0) {
        tlog[w] = td + bt2[0];
        glog[w] = gd + bw2[tgt];
    }
}

// ---------------------------------------------------------------------------
// K3: fp8 GEMM + fused sum-exp, A-in-registers, high-occupancy.
// Grid (40 col-groups, 49 row-strips) = 1960 blocks, 4 waves/block, each
// wave owns a distinct 64-row slice (row0 = by*256 + wid*64). All 4 waves
// share the 64-col B tile (16 KB, double-buffered, 32 KB LDS). A panel
// (64 rows x K=256 fp8) in 64 VGPRs, loaded once (PK layout). 4 iterations
// of 64 cols; one barrier/iter; exp into per-lane PS; one butterfly + 16
// atomics per wave at end. (256,4): VGPR 120 <= 128 cap -> 4 blocks/CU.
// ---------------------------------------------------------------------------
__global__ __launch_bounds__(256, 4) void big_gemm(
        const unsigned char* __restrict__ X,
        const unsigned char* __restrict__ WbT,
        const float* __restrict__ bw2,
        float* __restrict__ rowsum) {
    __shared__ unsigned char Bs[2][64 * 256];    // 2 x 16 KB
    const int t = threadIdx.x;
    const int wid = t >> 6, lane = t & 63;
    const int l15 = lane & 15, l4 = lane >> 4;
    const int g = blockIdx.x;                    // col group: 4 tiles of 64
    const int row0 = blockIdx.y * 256 + wid * 64;  // wave's own 64 rows

    auto dmaB = [&](int buf, int tileIdx) {
        const unsigned char* Bg = WbT + (size_t)tileIdx * 64 * 256;
#pragma unroll
        for (int q = 0; q < 4; q++) {
            int base = q * 4096 + wid * 1024;    // wave-uniform dest
            int F = base + lane * 16;            // this lane's dest byte
            int cc = F >> 8;                     // dest col within tile
            int s = (F >> 4) & 15;               // dest granule slot
            int srcg = s ^ (cc & 15);            // swizzled source granule
            __builtin_amdgcn_global_load_lds(
                (const __attribute__((address_space(1))) unsigned int*)(Bg + cc * 256 + (srcg << 4)),
                (__attribute__((address_space(3))) unsigned int*)(&Bs[buf][0] + base),
                16, 0, 0);
        }
    };

    dmaB(0, g * 4);

    // ---- A panel: 64 rows x K=256 in 64 VGPRs (PK layout: direct 16B loads)
    lng2 apan[4][4];
    {
        const unsigned char* Ag = X + (size_t)row0 * 256;
#pragma unroll
        for (int mi = 0; mi < 4; mi++)
#pragma unroll
            for (int p = 0; p < 4; p++)
                apan[mi][p] = *(const lng2*)(Ag + (mi * 16 + l15) * 256 + p * 64 + l4 * 16);
    }
    __syncthreads();   // drains DMA for iter 0 too

    float PS[4][4] = {};

#pragma unroll 1
    for (int it = 0; it < 4; it++) {
        if (it < 3) dmaB((it + 1) & 1, g * 4 + it + 1);
        const unsigned char* Bb = &Bs[it & 1][0];
        f32x4 acc[4][4] = {};
#pragma unroll
        for (int p = 0; p < 4; p++) {
            lng2 b[4];
#pragma unroll
            for (int ni = 0; ni < 4; ni++) {
                int cc = ni * 16 + l15;
                b[ni] = *(const lng2*)(Bb + cc * 256 + (((p * 4 + l4) ^ (cc & 15)) << 4));
            }
#pragma unroll
            for (int mi = 0; mi < 4; mi++)
#pragma unroll
                for (int ni = 0; ni < 4; ni++) {
                    acc[mi][ni] = __builtin_amdgcn_mfma_f32_16x16x32_fp8_fp8(
                        apan[mi][p].x, b[ni].x, acc[mi][ni], 0, 0, 0);
                    acc[mi][ni] = __builtin_amdgcn_mfma_f32_16x16x32_fp8_fp8(
                        apan[mi][p].y, b[ni].y, acc[mi][ni], 0, 0, 0);
                }
        }
        // ---- epilogue: exp(logit + bias) into per-lane partials ----
#pragma unroll
        for (int ni = 0; ni < 4; ni++) {
            int col = (g * 4 + it) * 64 + ni * 16 + l15;
            float bias = (col < V_SZ) ? bw2[col] : -__builtin_inff();
#pragma unroll
            for (int mi = 0; mi < 4; mi++)
#pragma unroll
                for (int r = 0; r < 4; r++)
                    PS[mi][r] += __expf(acc[mi][ni][r] + bias);
        }
        __syncthreads();
    }
    // ---- one butterfly + atomics per wave ----
#pragma unroll
    for (int mi = 0; mi < 4; mi++)
#pragma unroll
        for (int r = 0; r < 4; r++) {
            float v = PS[mi][r];
            v += __shfl_xor(v, 1); v += __shfl_xor(v, 2);
            v += __shfl_xor(v, 4); v += __shfl_xor(v, 8);
            if (l15 == 0)
                atomicAdd(&rowsum[row0 + mi * 16 + l4 * 4 + r], v);
        }
}

// ---------------------------------------------------------------------------
// K4: build tables in LDS + CKY DP. 16 blocks (one per batch), 1024 thr.
// 16 lanes per cell i; TWO-PASS logsumexp per gap: pass 1 computes scores
// into regs (independent loads, pipelined) + shuffle-max; pass 2 does
// independent expf + shuffle-add. One barrier per gap (cells of gap g only
// read gaps < g, so no pre-write barrier needed).
// ---------------------------------------------------------------------------
__global__ __launch_bounds__(1024) void dp_kernel(const float* __restrict__ tlog,
                          const float* __restrict__ glog,
                          const float* __restrict__ rowsum,
                          float* __restrict__ out) {
    __shared__ float Tl[1600], SHWl[1600], REl[1600];
    const int t = threadIdx.x;
    const int b = blockIdx.x;
    const float NEGINF = -__builtin_inff();
    for (int idx = t; idx < 1600; idx += 1024) {
        Tl[idx] = NEGINF; SHWl[idx] = NEGINF; REl[idx] = NEGINF;
    }
    __syncthreads();
    for (int p = t; p < NPAIR; p += 1024) {
        int i = 0, rem = p, len = L_SEQ - 1;
        while (rem >= len) { rem -= len; len--; i++; }
        int j = i + 1 + rem;
        int row = p * 16 + b;
        float tl = tlog[row];
        float re_v = (tl >= 0.f) ? -log1pf(__expf(-tl)) : (tl - log1pf(__expf(tl)));
        float sh_v = (tl <= 0.f) ? -log1pf(__expf(tl)) : (-tl - log1pf(__expf(-tl)));
        float wlp = glog[row] - __logf(rowsum[row]);
        SHWl[i * 40 + j] = sh_v + wlp;
        REl[i * 40 + j] = re_v;
    }
    if (t == 0) {
        int row = NPAIR * 16 + b;           // init cell
        Tl[0 * 40 + 1] = glog[row] - __logf(rowsum[row]);
    }
    if (t >= 1 && t <= 38) Tl[t * 40 + t + 1] = 0.f;
    __syncthreads();
    const int tg = t >> 4, li = t & 15;     // cell index i = tg, lane-in-group
    for (int gap = 2; gap <= L_SEQ - 1; gap++) {
        int n_i = L_SEQ - gap;
        int i = tg, j = tg + gap;
        float vbuf[3];
        int c = 0;
        float m = NEGINF;
        if (i < n_i) {
            for (int k = i + 1 + li; k < j; k += 16) {
                float v = Tl[i * 40 + k] + Tl[k * 40 + j]
                        + SHWl[i * 40 + k] + REl[k * 40 + j];
                vbuf[c++] = v;
                m = fmaxf(m, v);
            }
        }
        m = fmaxf(m, __shfl_xor(m, 1));
        m = fmaxf(m, __shfl_xor(m, 2));
        m = fmaxf(m, __shfl_xor(m, 4));
        m = fmaxf(m, __shfl_xor(m, 8));
        float s = 0.f;
        for (int q = 0; q < c; q++) s += __expf(vbuf[q] - m);
        s += __shfl_xor(s, 1);
        s += __shfl_xor(s, 2);
        s += __shfl_xor(s, 4);
        s += __shfl_xor(s, 8);
        if (i < n_i && li == 0) Tl[i * 40 + j] = m + __logf(s);
        __syncthreads();
    }
    if (t == 0) out[b] = Tl[39];
}

// ---------------------------------------------------------------------------
extern "C" void kernel_launch(void* const* d_in, const int* in_sizes, int n_in,
                              void* d_out, int out_size, void* d_ws, size_t ws_size,
                              hipStream_t stream) {
    const float* h        = (const float*)d_in[0];
    const int*   sentence = (const int*)d_in[1];
    const float* Wt1      = (const float*)d_in[2];
    const float* bt1      = (const float*)d_in[3];
    const float* Wt2      = (const float*)d_in[4];
    const float* bt2      = (const float*)d_in[5];
    const float* Ww1      = (const float*)d_in[6];
    const float* bw1      = (const float*)d_in[7];
    const float* Ww2      = (const float*)d_in[8];
    const float* bw2      = (const float*)d_in[9];
    float* out = (float*)d_out;

    char* ws = (char*)d_ws;
    size_t off = 0;
    float* UV = (float*)(ws + off);                    off += 4ull * 640 * 256 * 4;
    unsigned char* X = (unsigned char*)(ws + off);     off += (size_t)M_ROWS * 256;
    unsigned char* WbT = (unsigned char*)(ws + off);   off += (size_t)V_PAD * 256;
    float* WwT = (float*)(ws + off);                   off += (size_t)V_PAD * 256 * 4;
    float* rowsum = (float*)(ws + off);                off += (size_t)M_ROWS * 4;
    float* tlog = (float*)(ws + off);                  off += (size_t)M_ROWS * 4;
    float* glog = (float*)(ws + off);                  off += (size_t)M_ROWS * 4;

    const int zero_blocks = (M_ROWS + 255) / 256;      // 49
    prep_kernel<<<2880 + zero_blocks, 256, 0, stream>>>(
        Ww2, WwT, WbT, h, Wt1, Ww1, UV, rowsum);
    build_rows<<<M_ROWS / 4, 256, 0, stream>>>(UV, sentence, bt1, bw1, Wt2, bt2,
                                               WwT, bw2, X, tlog, glog);
    big_gemm<<<dim3(40, 49), 256, 0, stream>>>(X, WbT, bw2, rowsum);
    dp_kernel<<<16, 1024, 0, stream>>>(tlog, glog, rowsum, out);
}

// Round 9
// 248.173 us; speedup vs baseline: 1.3086x; 1.1339x over previous
//
#include <hip/hip_runtime.h>
#include <hip/hip_bf16.h>

#define L_SEQ 40
#define B_SZ  16
#define V_SZ  10000
#define V_PAD 10240
#define NPAIR 780
#define NROWP 784                 // 780 pairs + 1 init row + 3 pad "pairs"
#define M_ROWS (NROWP * B_SZ)     // 12544 rows = 49 strips of 256

typedef __attribute__((ext_vector_type(4))) float f32x4;
typedef __attribute__((ext_vector_type(2))) long lng2;

// ---------------------------------------------------------------------------
// float -> OCP e4m3fn. Prefer HW cvt; hand-rolled RNE fallback.
// ---------------------------------------------------------------------------
#if __has_builtin(__builtin_amdgcn_cvt_pk_fp8_f32)
__device__ __forceinline__ unsigned int pack4_fp8(float x0, float x1, float x2, float x3) {
    int lo = __builtin_amdgcn_cvt_pk_fp8_f32(x0, x1, 0, false);
    int full = __builtin_amdgcn_cvt_pk_fp8_f32(x2, x3, lo, true);
    return (unsigned int)full;
}
#else
__device__ __forceinline__ unsigned char f2e4m3(float f) {
    unsigned u = __float_as_uint(f);
    unsigned s = (u >> 24) & 0x80u;
    if ((u & 0x7FFFFFFFu) == 0) return (unsigned char)s;
    int E = (int)((u >> 23) & 0xFF) - 127 + 7;
    unsigned m = u & 0x7FFFFFu;
    if (E >= 16) return (unsigned char)(s | 0x7E);
    if (E >= 1) {
        unsigned keep = m >> 20, rest = m & 0xFFFFFu;
        keep += (rest > 0x80000u) || (rest == 0x80000u && (keep & 1));
        if (keep == 8) { keep = 0; E++; if (E >= 16) return (unsigned char)(s | 0x7E); }
        return (unsigned char)(s | (E << 3) | keep);
    }
    int shift = 1 - E;
    if (shift > 10) return (unsigned char)s;
    unsigned full = 0x800000u | m;
    unsigned sh = 20 + shift;
    unsigned keep = full >> sh, rem = full & ((1u << sh) - 1), half = 1u << (sh - 1);
    keep += (rem > half) || (rem == half && (keep & 1));
    if (keep >= 8) return (unsigned char)(s | (1 << 3));
    return (unsigned char)(s | keep);
}
__device__ __forceinline__ unsigned int pack4_fp8(float x0, float x1, float x2, float x3) {
    return (unsigned int)f2e4m3(x0) | ((unsigned int)f2e4m3(x1) << 8)
         | ((unsigned int)f2e4m3(x2) << 16) | ((unsigned int)f2e4m3(x3) << 24);
}
#endif

// fast tanh via HW exp: tanh(x) = (e^{2x}-1)/(e^{2x}+1). err ~1e-7, ~6 VALU ops.
__device__ __forceinline__ float ftanh(float x) {
    x = fminf(20.f, fmaxf(-20.f, x));
    float t = __expf(2.f * x);
    return (t - 1.f) * __frcp_rn(t + 1.f);
}

// PK layout: byte k of a 256-B row stored at pos = p*64 + l4*16 + h*8 + j
// where k = (2p+h)*32 + l4*8 + j. A lane's 16 B at (p, l4) covers the two
// k-steps 2p (low 8B) and 2p+1 (high 8B) of its MFMA fragment.

// ---------------------------------------------------------------------------
// K1: fused prep. [0,2560): transpose Ww2 -> WwT fp32 [10240,256] + WbT fp8 PK;
//     [2560,2880): UV = h @ {Wt1,Ww1} halves; rest: zero rowsum.
// ---------------------------------------------------------------------------
__global__ __launch_bounds__(256) void prep_kernel(
        const float* __restrict__ Ww2, float* __restrict__ WwT,
        unsigned char* __restrict__ WbT,
        const float* __restrict__ h, const float* __restrict__ Wt1,
        const float* __restrict__ Ww1, float* __restrict__ UV,
        float* __restrict__ rowsum) {
    const int bx = blockIdx.x;
    const int t = threadIdx.x;
    __shared__ float tile[32][33];
    __shared__ float hs[8 * 512];
    if (bx < 2560) {
        int v0 = (bx % 320) * 32;
        int K8 = bx / 320;           // k-tile index, k0 = K8*32
        int k0 = K8 * 32;
        int tx = t & 31, ty = t >> 5;   // 32 x 8
#pragma unroll
        for (int r = 0; r < 4; r++) {
            int k = k0 + ty + r * 8;
            int v = v0 + tx;
            tile[ty + r * 8][tx] = (v < V_SZ) ? Ww2[k * V_SZ + v] : 0.0f;   // tile[k][v]
        }
        __syncthreads();
        // fp32 transposed write (only real vocab rows; pads unused by gather)
#pragma unroll
        for (int r = 0; r < 4; r++) {
            int vrow = ty + r * 8;
            if (v0 + vrow < V_SZ)
                WwT[(v0 + vrow) * 256 + (k0 + tx)] = tile[tx][vrow];
        }
        // fp8 PK write: thread -> (col v2, 4 consecutive k)
        int v2 = t >> 3;                 // 0..31
        int kq = 4 * (t & 7);            // local k base 0..28
        unsigned int pk = pack4_fp8(tile[kq][v2], tile[kq + 1][v2],
                                    tile[kq + 2][v2], tile[kq + 3][v2]);
        // PK uint index for global k = K8*32 + kq:
        int idx = (K8 >> 1) * 16 + ((t & 7) >> 1) * 4 + (K8 & 1) * 2 + (t & 1);
        ((unsigned int*)WbT)[(v0 + v2) * 64 + idx] = pk;
    } else if (bx < 2880) {
        int ub = bx - 2560;
        int which = ub / 80;         // 0:Ut 1:Vt 2:Uw 3:Vw
        int m0 = (ub % 80) * 8;
        const float4* src = (const float4*)(h + (size_t)m0 * 512);
        float4* dst4 = (float4*)hs;
#pragma unroll
        for (int v = 0; v < 4; v++) dst4[v * 256 + t] = src[v * 256 + t];
        __syncthreads();
        const float* W = ((which < 2) ? Wt1 : Ww1) + ((which & 1) ? 512 * 256 : 0);
        float acc[8] = {};
        for (int f = 0; f < 512; f += 4) {
            float w0 = W[(f + 0) * 256 + t];
            float w1 = W[(f + 1) * 256 + t];
            float w2 = W[(f + 2) * 256 + t];
            float w3 = W[(f + 3) * 256 + t];
#pragma unroll
            for (int r = 0; r < 8; r++) {
                acc[r] += hs[r * 512 + f] * w0 + hs[r * 512 + f + 1] * w1
                        + hs[r * 512 + f + 2] * w2 + hs[r * 512 + f + 3] * w3;
            }
        }
        float* dst = UV + ((size_t)which * 640 + m0) * 256;
#pragma unroll
        for (int r = 0; r < 8; r++) dst[r * 256 + t] = acc[r];
    } else {
        int idx = (bx - 2880) * 256 + t;
        if (idx < M_ROWS) rowsum[idx] = 0.0f;
    }
}

// ---------------------------------------------------------------------------
// K2: per (pair,b) row: X = fp8(tanh(Uw[i]+Vw[j]+bw1)) in PK order;
//     tlog/glog fp32 exact. One wave per row; p==780 is the init cell.
// ---------------------------------------------------------------------------
__global__ void build_rows(const float* __restrict__ UV,
                           const int* __restrict__ sentence,
                           const float* __restrict__ bt1,
                           const float* __restrict__ bw1,
                           const float* __restrict__ Wt2,
                           const float* __restrict__ bt2,
                           const float* __restrict__ WwT,
                           const float* __restrict__ bw2,
                           unsigned char* __restrict__ X,
                           float* __restrict__ tlog,
                           float* __restrict__ glog) {
    int w = blockIdx.x * 4 + (threadIdx.x >> 6);
    int lane = threadIdx.x & 63;
    int p = w >> 4, b = w & 15;
    int i = 0, j = 0;
    if (p < NPAIR) {
        int rem = p, len = L_SEQ - 1;
        while (rem >= len) { rem -= len; len--; i++; }
        j = i + 1 + rem;
    }
    int j1 = (j + 1 < L_SEQ) ? j + 1 : L_SEQ - 1;
    int tgt = sentence[j1 * B_SZ + b];
    const float4 ut = ((const float4*)(UV + 0 * 640 * 256 + (i * B_SZ + b) * 256))[lane];
    const float4 vt = ((const float4*)(UV + 1 * 640 * 256 + (j * B_SZ + b) * 256))[lane];
    const float4 uw = ((const float4*)(UV + 2 * 640 * 256 + (i * B_SZ + b) * 256))[lane];
    const float4 vw = ((const float4*)(UV + 3 * 640 * 256 + (j * B_SZ + b) * 256))[lane];
    const float4 bt = ((const float4*)bt1)[lane];
    const float4 bw = ((const float4*)bw1)[lane];
    const float4 w2 = ((const float4*)Wt2)[lane];
    const float4 wc = ((const float4*)(WwT + (size_t)tgt * 256))[lane];
    float xt0 = ftanh(ut.x + vt.x + bt.x), xt1 = ftanh(ut.y + vt.y + bt.y);
    float xt2 = ftanh(ut.z + vt.z + bt.z), xt3 = ftanh(ut.w + vt.w + bt.w);
    float xw0 = ftanh(uw.x + vw.x + bw.x), xw1 = ftanh(uw.y + vw.y + bw.y);
    float xw2 = ftanh(uw.z + vw.z + bw.z), xw3 = ftanh(uw.w + vw.w + bw.w);
    // PK uint index for k0 = lane*4:
    int pki = (lane >> 4) * 16 + ((lane >> 1) & 3) * 4 + ((lane >> 3) & 1) * 2 + (lane & 1);
    ((unsigned int*)X)[w * 64 + pki] = pack4_fp8(xw0, xw1, xw2, xw3);
    float td = xt0 * w2.x + xt1 * w2.y + xt2 * w2.z + xt3 * w2.w;
    float gd = xw0 * wc.x + xw1 * wc.y + xw2 * wc.z + xw3 * wc.w;
#pragma unroll
    for (int off = 32; off >= 1; off >>= 1) {
        td += __shfl_xor(td, off);
        gd += __shfl_xor(gd, off);
    }
    if (lane == 0) {
        tlog[w] = td + bt2[0];
        glog[w] = gd + bw2[tgt];
    }
}

// ---------------------------------------------------------------------------
// K3: fp8 GEMM + fused sum-exp, A-in-registers.
// Grid (40 col-groups, 49 row-strips) = 1960 blocks, 4 waves/block, each
// wave owns a distinct 64-row slice (row0 = by*256 + wid*64). All 4 waves
// share the 64-col B tile (16 KB, double-buffered, 32 KB LDS). A panel
// (64 rows x K=256 fp8) in 64 VGPRs, loaded once (PK layout). 4 iterations
// of 64 cols; one barrier/iter; exp into per-lane PS; one butterfly + 16
// atomics per wave at end.
// LAUNCH BOUNDS: (256,3) -> VGPR cap 170, measured 120, NO SPILL.
// (256,4) caps VGPR at 128 => A-panel spills to scratch: 253 MB FETCH /
// 239 MB WRITE, 130 us (R8). Do not raise the wave bound on this kernel.
// ---------------------------------------------------------------------------
__global__ __launch_bounds__(256, 3) void big_gemm(
        const unsigned char* __restrict__ X,
        const unsigned char* __restrict__ WbT,
        const float* __restrict__ bw2,
        float* __restrict__ rowsum) {
    __shared__ unsigned char Bs[2][64 * 256];    // 2 x 16 KB
    const int t = threadIdx.x;
    const int wid = t >> 6, lane = t & 63;
    const int l15 = lane & 15, l4 = lane >> 4;
    const int g = blockIdx.x;                    // col group: 4 tiles of 64
    const int row0 = blockIdx.y * 256 + wid * 64;  // wave's own 64 rows

    auto dmaB = [&](int buf, int tileIdx) {
        const unsigned char* Bg = WbT + (size_t)tileIdx * 64 * 256;
#pragma unroll
        for (int q = 0; q < 4; q++) {
            int base = q * 4096 + wid * 1024;    // wave-uniform dest
            int F = base + lane * 16;            // this lane's dest byte
            int cc = F >> 8;                     // dest col within tile
            int s = (F >> 4) & 15;               // dest granule slot
            int srcg = s ^ (cc & 15);            // swizzled source granule
            __builtin_amdgcn_global_load_lds(
                (const __attribute__((address_space(1))) unsigned int*)(Bg + cc * 256 + (srcg << 4)),
                (__attribute__((address_space(3))) unsigned int*)(&Bs[buf][0] + base),
                16, 0, 0);
        }
    };

    dmaB(0, g * 4);

    // ---- A panel: 64 rows x K=256 in 64 VGPRs (PK layout: direct 16B loads)
    lng2 apan[4][4];
    {
        const unsigned char* Ag = X + (size_t)row0 * 256;
#pragma unroll
        for (int mi = 0; mi < 4; mi++)
#pragma unroll
            for (int p = 0; p < 4; p++)
                apan[mi][p] = *(const lng2*)(Ag + (mi * 16 + l15) * 256 + p * 64 + l4 * 16);
    }
    __syncthreads();   // drains DMA for iter 0 too

    float PS[4][4] = {};

#pragma unroll 1
    for (int it = 0; it < 4; it++) {
        if (it < 3) dmaB((it + 1) & 1, g * 4 + it + 1);
        const unsigned char* Bb = &Bs[it & 1][0];
        f32x4 acc[4][4] = {};
#pragma unroll
        for (int p = 0; p < 4; p++) {
            lng2 b[4];
#pragma unroll
            for (int ni = 0; ni < 4; ni++) {
                int cc = ni * 16 + l15;
                b[ni] = *(const lng2*)(Bb + cc * 256 + (((p * 4 + l4) ^ (cc & 15)) << 4));
            }
#pragma unroll
            for (int mi = 0; mi < 4; mi++)
#pragma unroll
                for (int ni = 0; ni < 4; ni++) {
                    acc[mi][ni] = __builtin_amdgcn_mfma_f32_16x16x32_fp8_fp8(
                        apan[mi][p].x, b[ni].x, acc[mi][ni], 0, 0, 0);
                    acc[mi][ni] = __builtin_amdgcn_mfma_f32_16x16x32_fp8_fp8(
                        apan[mi][p].y, b[ni].y, acc[mi][ni], 0, 0, 0);
                }
        }
        // ---- epilogue: exp(logit + bias) into per-lane partials ----
#pragma unroll
        for (int ni = 0; ni < 4; ni++) {
            int col = (g * 4 + it) * 64 + ni * 16 + l15;
            float bias = (col < V_SZ) ? bw2[col] : -__builtin_inff();
#pragma unroll
            for (int mi = 0; mi < 4; mi++)
#pragma unroll
                for (int r = 0; r < 4; r++)
                    PS[mi][r] += __expf(acc[mi][ni][r] + bias);
        }
        __syncthreads();
    }
    // ---- one butterfly + atomics per wave ----
#pragma unroll
    for (int mi = 0; mi < 4; mi++)
#pragma unroll
        for (int r = 0; r < 4; r++) {
            float v = PS[mi][r];
            v += __shfl_xor(v, 1); v += __shfl_xor(v, 2);
            v += __shfl_xor(v, 4); v += __shfl_xor(v, 8);
            if (l15 == 0)
                atomicAdd(&rowsum[row0 + mi * 16 + l4 * 4 + r], v);
        }
}

// ---------------------------------------------------------------------------
// K4: build tables in LDS + CKY DP. 16 blocks (one per batch), 1024 thr.
// 16 lanes per cell i; TWO-PASS logsumexp per gap: pass 1 computes scores
// into regs (independent loads, pipelined) + shuffle-max; pass 2 does
// independent expf + shuffle-add. One barrier per gap.
// ---------------------------------------------------------------------------
__global__ __launch_bounds__(1024) void dp_kernel(const float* __restrict__ tlog,
                          const float* __restrict__ glog,
                          const float* __restrict__ rowsum,
                          float* __restrict__ out) {
    __shared__ float Tl[1600], SHWl[1600], REl[1600];
    const int t = threadIdx.x;
    const int b = blockIdx.x;
    const float NEGINF = -__builtin_inff();
    for (int idx = t; idx < 1600; idx += 1024) {
        Tl[idx] = NEGINF; SHWl[idx] = NEGINF; REl[idx] = NEGINF;
    }
    __syncthreads();
    for (int p = t; p < NPAIR; p += 1024) {
        int i = 0, rem = p, len = L_SEQ - 1;
        while (rem >= len) { rem -= len; len--; i++; }
        int j = i + 1 + rem;
        int row = p * 16 + b;
        float tl = tlog[row];
        float re_v = (tl >= 0.f) ? -log1pf(__expf(-tl)) : (tl - log1pf(__expf(tl)));
        float sh_v = (tl <= 0.f) ? -log1pf(__expf(tl)) : (-tl - log1pf(__expf(-tl)));
        float wlp = glog[row] - __logf(rowsum[row]);
        SHWl[i * 40 + j] = sh_v + wlp;
        REl[i * 40 + j] = re_v;
    }
    if (t == 0) {
        int row = NPAIR * 16 + b;           // init cell
        Tl[0 * 40 + 1] = glog[row] - __logf(rowsum[row]);
    }
    if (t >= 1 && t <= 38) Tl[t * 40 + t + 1] = 0.f;
    __syncthreads();
    const int tg = t >> 4, li = t & 15;     // cell index i = tg, lane-in-group
    for (int gap = 2; gap <= L_SEQ - 1; gap++) {
        int n_i = L_SEQ - gap;
        int i = tg, j = tg + gap;
        float vbuf[3];
        int c = 0;
        float m = NEGINF;
        if (i < n_i) {
            for (int k = i + 1 + li; k < j; k += 16) {
                float v = Tl[i * 40 + k] + Tl[k * 40 + j]
                        + SHWl[i * 40 + k] + REl[k * 40 + j];
                vbuf[c++] = v;
                m = fmaxf(m, v);
            }
        }
        m = fmaxf(m, __shfl_xor(m, 1));
        m = fmaxf(m, __shfl_xor(m, 2));
        m = fmaxf(m, __shfl_xor(m, 4));
        m = fmaxf(m, __shfl_xor(m, 8));
        float s = 0.f;
        for (int q = 0; q < c; q++) s += __expf(vbuf[q] - m);
        s += __shfl_xor(s, 1);
        s += __shfl_xor(s, 2);
        s += __shfl_xor(s, 4);
        s += __shfl_xor(s, 8);
        if (i < n_i && li == 0) Tl[i * 40 + j] = m + __logf(s);
        __syncthreads();
    }
    if (t == 0) out[b] = Tl[39];
}

// ---------------------------------------------------------------------------
extern "C" void kernel_launch(void* const* d_in, const int* in_sizes, int n_in,
                              void* d_out, int out_size, void* d_ws, size_t ws_size,
                              hipStream_t stream) {
    const float* h        = (const float*)d_in[0];
    const int*   sentence = (const int*)d_in[1];
    const float* Wt1      = (const float*)d_in[2];
    const float* bt1      = (const float*)d_in[3];
    const float* Wt2      = (const float*)d_in[4];
    const float* bt2      = (const float*)d_in[5];
    const float* Ww1      = (const float*)d_in[6];
    const float* bw1      = (const float*)d_in[7];
    const float* Ww2      = (const float*)d_in[8];
    const float* bw2      = (const float*)d_in[9];
    float* out = (float*)d_out;

    char* ws = (char*)d_ws;
    size_t off = 0;
    float* UV = (float*)(ws + off);                    off += 4ull * 640 * 256 * 4;
    unsigned char* X = (unsigned char*)(ws + off);     off += (size_t)M_ROWS * 256;
    unsigned char* WbT = (unsigned char*)(ws + off);   off += (size_t)V_PAD * 256;
    float* WwT = (float*)(ws + off);                   off += (size_t)V_PAD * 256 * 4;
    float* rowsum = (float*)(ws + off);                off += (size_t)M_ROWS * 4;
    float* tlog = (float*)(ws + off);                  off += (size_t)M_ROWS * 4;
    float* glog = (float*)(ws + off);                  off += (size_t)M_ROWS * 4;

    const int zero_blocks = (M_ROWS + 255) / 256;      // 49
    prep_kernel<<<2880 + zero_blocks, 256, 0, stream>>>(
        Ww2, WwT, WbT, h, Wt1, Ww1, UV, rowsum);
    build_rows<<<M_ROWS / 4, 256, 0, stream>>>(UV, sentence, bt1, bw1, Wt2, bt2,
                                               WwT, bw2, X, tlog, glog);
    big_gemm<<<dim3(40, 49), 256, 0, stream>>>(X, WbT, bw2, rowsum);
    dp_kernel<<<16, 1024, 0, stream>>>(tlog, glog, rowsum, out);
}